// Round 5
// baseline (312.279 us; speedup 1.0000x reference)
//
#include <hip/hip_runtime.h>
#include <cstdint>
#include <math.h>

// GeometricAttention: B=4,H=8,N=2048, D = 8*16 (mv, IPF on q) + 16 (s) = 144
// R5: BM=64, 4 waves = 2 row-groups(32 Q-rows) x 2 col-halves(32 KV cols) -> 1024
// blocks, 12 waves/CU. Fragment-ordered conflict-free K/V^T packing (R4). Cross-wave
// softmax exchange via 1KB LDS folded into the mid barrier; O pair-merge in epilogue.

#define BH    32
#define N_    2048
#define DMV   128
#define DS    16
#define D_    144
#define BM    64           // Q rows per block (2 row-groups x 32)
#define BN    64           // KV rows per iteration
#define NKIT  (N_ / BN)    // 32
#define PSTR2 40           // sP row stride (elems): 80B -> 2-way free, 16B-aligned b128
#define KTILE_E  10240     // K tile: 20 frags x 512 elems (k 0..159, zero-pad >143)
#define VTILE_E  9216      // V^T tile: 18 frags x 512 elems
#define KP_BYTES ((size_t)BH * NKIT * KTILE_E * 2)   // 20.97 MB
#define QSCALE 0.12022458674074693f  // (1/12) * log2(e)

typedef __bf16 bf16_8 __attribute__((ext_vector_type(8)));
typedef float  f32x4  __attribute__((ext_vector_type(4)));

#define GLOAD_LDS16(g, l)                                                     \
  __builtin_amdgcn_global_load_lds(                                           \
      (const __attribute__((address_space(1))) void*)(g),                     \
      (__attribute__((address_space(3))) void*)(l), 16, 0, 0)

__device__ __forceinline__ f32x4 mfma16(bf16_8 a, bf16_8 b, f32x4 c) {
  return __builtin_amdgcn_mfma_f32_16x16x32_bf16(a, b, c, 0, 0, 0);
}

// ---------------- pre-pass 1: K -> fragment-ordered bf16 tiles (unchanged R4) --------
__global__ __launch_bounds__(256)
void pack_k(const float* __restrict__ kmv, const float* __restrict__ ks_,
            __bf16* __restrict__ kp) {
  const int tile = blockIdx.x;                    // bh*32 + it
  const int t = threadIdx.x;
  __bf16* dst = kp + (size_t)tile * KTILE_E;
#pragma unroll
  for (int u = 0; u < 5; ++u) {
    int c = t + 256 * u;                          // < 1280
    int f = c >> 6, r = c & 63;
    int nt = f / 5, ks = f - nt * 5;
    int quad = r >> 4, l15 = r & 15;
    int n = tile * 64 + nt * 16 + l15;
    int k = ks * 32 + quad * 8;
    bf16_8 o;
    if (k < DMV) {
      const f32x4* p = (const f32x4*)(kmv + (size_t)n * DMV + k);
      f32x4 a = p[0], b = p[1];
#pragma unroll
      for (int j = 0; j < 8; ++j) o[j] = (__bf16)((j < 4) ? a[j] : b[j - 4]);
    } else if (k < D_) {
      const f32x4* p = (const f32x4*)(ks_ + (size_t)n * DS + (k - DMV));
      f32x4 a = p[0], b = p[1];
#pragma unroll
      for (int j = 0; j < 8; ++j) o[j] = (__bf16)((j < 4) ? a[j] : b[j - 4]);
    } else {
#pragma unroll
      for (int j = 0; j < 8; ++j) o[j] = (__bf16)0.0f;
    }
    *(bf16_8*)(dst + (size_t)c * 8) = o;
  }
}

// ---------------- pre-pass 2: V^T -> fragment-ordered bf16 tiles (unchanged R4) ------
#define TSTR 156
__global__ __launch_bounds__(256)
void pack_vt(const float* __restrict__ vmv, const float* __restrict__ vs,
             __bf16* __restrict__ vt) {
  __shared__ __bf16 sT[64 * TSTR];
  const int tile = blockIdx.x;                    // bh*32 + it
  const int t = threadIdx.x;
  {
    const int n = t >> 2, c4 = t & 3;
    const float* mv = vmv + (size_t)(tile * 64 + n) * DMV;
    const float* s  = vs  + (size_t)(tile * 64 + n) * DS;
    __bf16* row = &sT[n * TSTR];
    if (c4 < 3) {
#pragma unroll
      for (int i = 0; i < 9; ++i) {
        f32x4 x = *(const f32x4*)(mv + c4 * 36 + 4 * i);
#pragma unroll
        for (int j = 0; j < 4; ++j) row[c4 * 36 + 4 * i + j] = (__bf16)x[j];
      }
    } else {
#pragma unroll
      for (int i = 0; i < 5; ++i) {
        f32x4 x = *(const f32x4*)(mv + 108 + 4 * i);
#pragma unroll
        for (int j = 0; j < 4; ++j) row[108 + 4 * i + j] = (__bf16)x[j];
      }
#pragma unroll
      for (int i = 0; i < 4; ++i) {
        f32x4 x = *(const f32x4*)(s + 4 * i);
#pragma unroll
        for (int j = 0; j < 4; ++j) row[128 + 4 * i + j] = (__bf16)x[j];
      }
    }
  }
  __syncthreads();
  __bf16* dst = vt + (size_t)tile * VTILE_E;
  for (int c = t; c < 1152; c += 256) {
    int f = c >> 6, r = c & 63;
    int n9 = f >> 1, ks = f & 1;
    int quad = r >> 4, l15 = r & 15;
    int d = n9 * 16 + l15;
    int n0 = ks * 32 + quad * 8;
    bf16_8 o;
#pragma unroll
    for (int j = 0; j < 8; ++j) o[j] = sT[(n0 + j) * TSTR + d];
    *(bf16_8*)(dst + (size_t)c * 8) = o;
  }
}

// ---------------- Q fragment load: IPF sign + scale, fp32 -> bf16 --------------------
__device__ __forceinline__ bf16_8 load_q_frag(const float* qmv_row, const float* qs_row, int k0) {
  bf16_8 f;
  if (k0 < DMV) {
    const f32x4* p = (const f32x4*)(qmv_row + k0);
    f32x4 a = p[0], b = p[1];
    // IPF = [1,1,-1,-1,-1,-1,-1,-1, 1,1,1,1,1,1,-1,-1]; k0&8 selects which half.
    int hi = k0 & 8;
#pragma unroll
    for (int j = 0; j < 8; ++j) {
      float v = (j < 4) ? a[j] : b[j - 4];
      bool pos = hi ? (j < 6) : (j < 2);
      f[j] = (__bf16)(v * (pos ? QSCALE : -QSCALE));
    }
  } else if (k0 < D_) {
    const f32x4* p = (const f32x4*)(qs_row + (k0 - DMV));
    f32x4 a = p[0], b = p[1];
#pragma unroll
    for (int j = 0; j < 8; ++j) {
      float v = (j < 4) ? a[j] : b[j - 4];
      f[j] = (__bf16)(v * QSCALE);
    }
  } else {
#pragma unroll
    for (int j = 0; j < 8; ++j) f[j] = (__bf16)0.0f;
  }
  return f;
}

// ---------------- main flash kernel (256 thr: 2 row-groups x 2 col-halves) -----------
__global__ __launch_bounds__(256, 3)
void geo_attn_kernel(const float* __restrict__ q_mv, const float* __restrict__ q_s,
                     const __bf16* __restrict__ kp, const __bf16* __restrict__ vt,
                     float* __restrict__ out)
{
  __shared__ __align__(16) unsigned char smem[20480 + 18432 + 1024];  // 39936 B
  __bf16* sK  = (__bf16*)smem;            // 20480 B K frags; sP aliased after QK
  __bf16* sVT = (__bf16*)(smem + 20480);  // 18432 B V^T frags
  float2* sX  = (float2*)(smem + 38912);  // 1024 B cross-wave (pmx, psum) exchange
  float*  sM  = (float*)smem;             // epilogue pair-merge overlay

  const int tid  = threadIdx.x;
  const int w    = tid >> 6;        // wave 0..3
  const int lane = tid & 63;
  const int l15  = lane & 15;
  const int quad = lane >> 4;
  const int g    = w >> 1;          // row-group 0..1 (32 Q rows each)
  const int c    = w & 1;           // col-half 0..1 (32 KV cols each)
  const int bh    = blockIdx.y;
  const int qbase = blockIdx.x * BM;
  const size_t bh_n = (size_t)bh * N_;

  __bf16* sPw = sK + w * (32 * PSTR2);   // per-wave 32x40 P region (2560 B)

  // ---- Q fragments in registers (both c-waves of a pair load the same rows)
  bf16_8 qf[2][5];
#pragma unroll
  for (int rg = 0; rg < 2; ++rg) {
    int mrow = qbase + 32 * g + 16 * rg + l15;
    const float* qmv_row = q_mv + (bh_n + mrow) * DMV;
    const float* qs_row  = q_s  + (bh_n + mrow) * DS;
#pragma unroll
    for (int ks = 0; ks < 5; ++ks)
      qf[rg][ks] = load_q_frag(qmv_row, qs_row, ks * 32 + quad * 8);
  }

  f32x4 of[2][9];
#pragma unroll
  for (int rg = 0; rg < 2; ++rg)
#pragma unroll
    for (int n9 = 0; n9 < 9; ++n9)
#pragma unroll
      for (int r = 0; r < 4; ++r) of[rg][n9][r] = 0.0f;
  float m_i[2] = {-INFINITY, -INFINITY}, l_i[2] = {0.0f, 0.0f};

  const __bf16* kbase = kp + (size_t)bh * NKIT * KTILE_E;
  const __bf16* vbase = vt + (size_t)bh * NKIT * VTILE_E;

  for (int it = 0; it < NKIT; ++it) {
    // ======== stage K,V tiles via global->LDS DMA (contiguous 1024B chunks) ========
    {
      const __bf16* kt = kbase + (size_t)it * KTILE_E;
      const __bf16* vp = vbase + (size_t)it * VTILE_E;
      for (int i = w; i < 20; i += 4)
        GLOAD_LDS16(kt + i * 512 + lane * 8, &sK[i * 512 + lane * 8]);
      for (int i = w; i < 18; i += 4)
        GLOAD_LDS16(vp + i * 512 + lane * 8, &sVT[i * 512 + lane * 8]);
    }
    __syncthreads();   // B1: vmcnt drained -> tiles resident

    // ======== S^T = K Q^T on this wave's col-half (nt = 2c..2c+1) ========
    f32x4 sf[2][2];
#pragma unroll
    for (int rg = 0; rg < 2; ++rg)
#pragma unroll
      for (int nt2 = 0; nt2 < 2; ++nt2)
#pragma unroll
        for (int r = 0; r < 4; ++r) sf[rg][nt2][r] = 0.0f;
#pragma unroll
    for (int ks = 0; ks < 5; ++ks) {
#pragma unroll
      for (int nt2 = 0; nt2 < 2; ++nt2) {
        bf16_8 kb = *(const bf16_8*)&sK[((2 * c + nt2) * 5 + ks) * 512 + lane * 8];
        sf[0][nt2] = mfma16(kb, qf[0][ks], sf[0][nt2]);
        sf[1][nt2] = mfma16(kb, qf[1][ks], sf[1][nt2]);
      }
    }

    // ======== partial softmax over 32 local cols; post exchange data ========
    float pmx[2], ps[2];
#pragma unroll
    for (int rg = 0; rg < 2; ++rg) {
      float mx = sf[rg][0][0];
#pragma unroll
      for (int nt2 = 0; nt2 < 2; ++nt2)
#pragma unroll
        for (int r = 0; r < 4; ++r) mx = fmaxf(mx, sf[rg][nt2][r]);
      mx = fmaxf(mx, __shfl_xor(mx, 16));
      mx = fmaxf(mx, __shfl_xor(mx, 32));
      float rs = 0.0f;
#pragma unroll
      for (int nt2 = 0; nt2 < 2; ++nt2)
#pragma unroll
        for (int r = 0; r < 4; ++r) {
          float e = __builtin_amdgcn_exp2f(sf[rg][nt2][r] - mx);
          sf[rg][nt2][r] = e;
          rs += e;
        }
      rs += __shfl_xor(rs, 16);
      rs += __shfl_xor(rs, 32);
      pmx[rg] = mx; ps[rg] = rs;
      if (quad == 0) sX[((g * 2 + rg) * 2 + c) * 16 + l15] = make_float2(mx, rs);
    }
    __syncthreads();   // B2: QK sK reads done (sP alias safe) + sX visible

    // ======== combine with partner half; write scaled P; rescale O ========
#pragma unroll
    for (int rg = 0; rg < 2; ++rg) {
      float2 ot = sX[((g * 2 + rg) * 2 + (1 - c)) * 16 + l15];
      float mnew = fmaxf(m_i[rg], fmaxf(pmx[rg], ot.x));
      float al  = __builtin_amdgcn_exp2f(m_i[rg] - mnew);
      float scm = __builtin_amdgcn_exp2f(pmx[rg] - mnew);
      float sco = __builtin_amdgcn_exp2f(ot.x - mnew);
      l_i[rg] = l_i[rg] * al + ps[rg] * scm + ot.y * sco;
      m_i[rg] = mnew;
      // P write: row m = rg*16+l15, local col = nt2*16 + quad*4 + r (scaled by scm)
#pragma unroll
      for (int nt2 = 0; nt2 < 2; ++nt2) {
        __bf16 pw[4];
#pragma unroll
        for (int r = 0; r < 4; ++r) pw[r] = (__bf16)(sf[rg][nt2][r] * scm);
        *(uint64_t*)&sPw[(rg * 16 + l15) * PSTR2 + nt2 * 16 + quad * 4] = *(uint64_t*)pw;
      }
      // alpha to O-row indexing (row quad*4+r): srclane = quad*16 + quad*4 + r
      float alr[4];
#pragma unroll
      for (int r = 0; r < 4; ++r) alr[r] = __shfl(al, 20 * quad + r);
#pragma unroll
      for (int n9 = 0; n9 < 9; ++n9)
#pragma unroll
        for (int r = 0; r < 4; ++r) of[rg][n9][r] *= alr[r];
    }
    asm volatile("s_waitcnt lgkmcnt(0)" ::: "memory");  // sPw wave-private

    // ======== O += P V over this wave's 32 KV cols (single K=32 step) ========
    {
      bf16_8 pa0 = *(const bf16_8*)&sPw[l15 * PSTR2 + quad * 8];
      bf16_8 pa1 = *(const bf16_8*)&sPw[(16 + l15) * PSTR2 + quad * 8];
#pragma unroll
      for (int n9 = 0; n9 < 9; ++n9) {
        bf16_8 vb = *(const bf16_8*)&sVT[(n9 * 2 + c) * 512 + lane * 8];
        of[0][n9] = mfma16(pa0, vb, of[0][n9]);
        of[1][n9] = mfma16(pa1, vb, of[1][n9]);
      }
    }
    __syncthreads();  // B3: all LDS reads done before next iteration's DMA
  }

  // ======== epilogue: merge col-half partials via LDS, O /= l, write fp32 ========
  float* out_mv = out;
  float* out_s  = out + (size_t)BH * N_ * DMV;
#pragma unroll
  for (int rg = 0; rg < 2; ++rg) {
    __syncthreads();
    if (c == 1) {
#pragma unroll
      for (int n9 = 0; n9 < 9; ++n9)
#pragma unroll
        for (int r = 0; r < 4; ++r)
          sM[(g * 16 + quad * 4 + r) * 148 + n9 * 16 + l15] = of[rg][n9][r];
    }
    __syncthreads();
    if (c == 0) {
      float linv[4];
#pragma unroll
      for (int r = 0; r < 4; ++r)
        linv[r] = __builtin_amdgcn_rcpf(__shfl(l_i[rg], 20 * quad + r));
#pragma unroll
      for (int n9 = 0; n9 < 9; ++n9) {
#pragma unroll
        for (int r = 0; r < 4; ++r) {
          int row = qbase + 32 * g + 16 * rg + quad * 4 + r;
          float val = (of[rg][n9][r] +
                       sM[(g * 16 + quad * 4 + r) * 148 + n9 * 16 + l15]) * linv[r];
          if (n9 < 8) out_mv[(bh_n + row) * DMV + n9 * 16 + l15] = val;
          else        out_s [(bh_n + row) * DS + l15] = val;
        }
      }
    }
  }
}

extern "C" void kernel_launch(void* const* d_in, const int* in_sizes, int n_in,
                              void* d_out, int out_size, void* d_ws, size_t ws_size,
                              hipStream_t stream) {
  (void)in_sizes; (void)n_in; (void)out_size; (void)ws_size;
  const float* q_mv = (const float*)d_in[0];
  const float* k_mv = (const float*)d_in[1];
  const float* v_mv = (const float*)d_in[2];
  const float* q_s  = (const float*)d_in[3];
  const float* k_s  = (const float*)d_in[4];
  const float* v_s  = (const float*)d_in[5];
  float* out = (float*)d_out;

  __bf16* kp = (__bf16*)d_ws;                              // 20,971,520 B
  __bf16* vt = (__bf16*)((char*)d_ws + KP_BYTES);          // 18,874,368 B

  pack_k<<<BH * NKIT, 256, 0, stream>>>(k_mv, k_s, kp);
  pack_vt<<<BH * NKIT, 256, 0, stream>>>(v_mv, v_s, vt);

  dim3 grid(N_ / BM, BH);
  geo_attn_kernel<<<grid, 256, 0, stream>>>(q_mv, q_s, kp, vt, out);
}